// Round 8
// baseline (260.558 us; speedup 1.0000x reference)
//
#include <hip/hip_runtime.h>
#include <hip/hip_bf16.h>
#include <math.h>
#include <stdint.h>

#define NROWS 1000000
#define NCOLS 100
#define NBINS 20
#define NB    19       // bin boundaries
#define W     50000u   // rows per bin
#define NH    2049     // buckets: 0 = catch-all (<0.5), 1..2048 = [0.5,1) in 2^-12 steps

// ---------- ws layout (dword offsets) ----------
#define HIST_DW 0u       // len 2052
#define BINS_DW 2052u    // len 80 dw = 40 doubles (byte 8208, 8-aligned)
#define ZERO_DW 2132u    // hist+bins zeroed inside k1
#define CONF_DW 2136u    // len 1000000 (byte 8544 = 534*16, 16B-aligned); sign bit = accuracy

__device__ __forceinline__ unsigned int bucket_of(unsigned int bits) {
    // bits = positive-f32 pattern. conf < 0.5 -> 0 (catch-all).
    if (bits < 0x3F000000u) return 0u;
    unsigned int t = (bits >> 12) - 258048u + 1u;   // 1..2048 for [0.5,1)
    return t > 2048u ? 2048u : t;
}

// ---------- K1: wave-cooperative row max/argmax (round-6 proven form) ------
// NOTE: launched TWICE this round as a timing probe — k1 is idempotent
// (re-zeros hist/bins and rewrites identical conf before any consumer).
// k1_dur = total - 151us (round-6 baseline with identical code, 1 launch).
__global__ __launch_bounds__(256) void k1_rowmax(const float* __restrict__ x,
                                                 const int* __restrict__ labels,
                                                 float* __restrict__ conf,
                                                 unsigned int* __restrict__ zero_region) {
    int gtid = blockIdx.x * 256 + threadIdx.x;
    if (gtid < (int)ZERO_DW) zero_region[gtid] = 0u;   // hist + bins

    int wave = gtid >> 6;
    int lane = threadIdx.x & 63;
    int half = lane >> 5;
    int l    = lane & 31;
    int nwaves = (gridDim.x * 256) >> 6;

    for (int rp = wave; rp < NROWS / 2; rp += nwaves) {
        int row = rp * 2 + half;
        const float4* r4 = reinterpret_cast<const float4*>(x + (size_t)row * NCOLS);
        float best = -1.0f;
        int bi = 999;
        if (l < 25) {
            float4 v = r4[l];
            best = v.x; bi = 4 * l;
            if (v.y > best) { best = v.y; bi = 4 * l + 1; }
            if (v.z > best) { best = v.z; bi = 4 * l + 2; }
            if (v.w > best) { best = v.w; bi = 4 * l + 3; }
        }
        #pragma unroll
        for (int mask = 16; mask >= 1; mask >>= 1) {
            float ov = __shfl_xor(best, mask);
            int   oi = __shfl_xor(bi,   mask);
            if (ov > best || (ov == best && oi < bi)) { best = ov; bi = oi; }
        }
        if (l == 0) {
            unsigned int cb = __float_as_uint(best);
            if (bi == labels[row]) cb |= 0x80000000u;
            conf[row] = __uint_as_float(cb);
        }
    }
}

// ---------- K2: 2049-bucket histogram, per-block LDS ----------
__global__ __launch_bounds__(512) void k2_hist(const float* __restrict__ conf,
                                               unsigned int* __restrict__ hist) {
    __shared__ unsigned int lh[NH];
    for (int i = threadIdx.x; i < NH; i += 512) lh[i] = 0u;
    __syncthreads();
    const uint4* c4 = reinterpret_cast<const uint4*>(conf);
    int stride = gridDim.x * 512;
    for (int i = blockIdx.x * 512 + threadIdx.x; i < NROWS / 4; i += stride) {
        uint4 v = c4[i];
        atomicAdd(&lh[bucket_of(v.x & 0x7FFFFFFFu)], 1u);
        atomicAdd(&lh[bucket_of(v.y & 0x7FFFFFFFu)], 1u);
        atomicAdd(&lh[bucket_of(v.z & 0x7FFFFFFFu)], 1u);
        atomicAdd(&lh[bucket_of(v.w & 0x7FFFFFFFu)], 1u);
    }
    __syncthreads();
    for (int i = threadIdx.x; i < NH; i += 512) {
        unsigned int c = lh[i];
        if (c) atomicAdd(&hist[i], c);
    }
}

// ---------- K3: per-block redundant scan+bounds, then split-accumulate ----
__global__ __launch_bounds__(256) void k3_accum(const float* __restrict__ conf,
                                                const unsigned int* __restrict__ hist,
                                                double* __restrict__ bins) {
    __shared__ unsigned int ptab[NH];   // prefix, later |= (slot+1)<<24 on boundary buckets
    __shared__ unsigned int s[256];
    __shared__ unsigned int bndS[NB];
    __shared__ float sFr[NB];
    __shared__ float sc[4][NBINS], sa[4][NBINS];
    int tid = threadIdx.x;

    // --- scan hist (2049) into ptab ---
    unsigned int loc[9];
    unsigned int tot = 0;
    int base = tid * 9;
    #pragma unroll
    for (int k = 0; k < 9; k++) {
        int idx = base + k;
        unsigned int v = (idx < NH) ? hist[idx] : 0u;
        loc[k] = tot; tot += v;
    }
    s[tid] = tot; __syncthreads();
    for (int off = 1; off < 256; off <<= 1) {
        unsigned int v = (tid >= off) ? s[tid - off] : 0u;
        __syncthreads();
        s[tid] += v;
        __syncthreads();
    }
    unsigned int excl = s[tid] - tot;
    #pragma unroll
    for (int k = 0; k < 9; k++) {
        int idx = base + k;
        if (idx < NH) ptab[idx] = excl + loc[k];
    }
    for (int i = tid; i < 4 * NBINS; i += 256) { (&sc[0][0])[i] = 0.f; (&sa[0][0])[i] = 0.f; }
    __syncthreads();

    // --- phase A: locate boundaries on the CLEAN prefix, save fr ---
    if (tid < NB) {
        unsigned int r = (unsigned int)(tid + 1) * W;
        int lo = 0, hi = NH - 1;
        while (lo < hi) {
            int mid = (lo + hi + 1) >> 1;
            if (ptab[mid] <= r) lo = mid; else hi = mid - 1;
        }
        unsigned int p = ptab[lo];
        if (p < r) {
            unsigned int cnt = ((lo + 1 < NH) ? ptab[lo + 1] : (unsigned int)NROWS) - p;
            bndS[tid] = (unsigned int)lo;
            sFr[tid]  = (float)(r - p) / (float)cnt;
        } else {
            bndS[tid] = 0xFFFFFFFFu;
        }
    }
    __syncthreads();
    // --- phase B: mark boundary buckets ---
    if (tid < NB && bndS[tid] != 0xFFFFFFFFu)
        ptab[bndS[tid]] |= (unsigned int)(tid + 1) << 24;
    __syncthreads();

    // --- main pass ---
    int wid = tid >> 6;
    const uint4* c4 = reinterpret_cast<const uint4*>(conf);
    int stride = gridDim.x * 256;
    for (int i = blockIdx.x * 256 + tid; i < NROWS / 4; i += stride) {
        uint4 q = c4[i];
        unsigned int bs[4] = { q.x, q.y, q.z, q.w };
        #pragma unroll
        for (int j = 0; j < 4; j++) {
            unsigned int raw = bs[j];
            float a = (float)(raw >> 31);
            unsigned int bits = raw & 0x7FFFFFFFu;
            float c = __uint_as_float(bits);
            unsigned int e = ptab[bucket_of(bits)];
            unsigned int t = e >> 24;
            if (t == 0u) {
                unsigned int bin = (e & 0xFFFFFFu) / W;
                atomicAdd(&sc[wid][bin], c); atomicAdd(&sa[wid][bin], a);
            } else {
                float fr = sFr[t - 1];
                atomicAdd(&sc[wid][t - 1], c * fr);
                atomicAdd(&sc[wid][t],     c * (1.f - fr));
                atomicAdd(&sa[wid][t - 1], a * fr);
                atomicAdd(&sa[wid][t],     a * (1.f - fr));
            }
        }
    }
    __syncthreads();
    if (tid < NBINS) {
        float tc = sc[0][tid] + sc[1][tid] + sc[2][tid] + sc[3][tid];
        float ta = sa[0][tid] + sa[1][tid] + sa[2][tid] + sa[3][tid];
        atomicAdd(&bins[tid],         (double)tc);
        atomicAdd(&bins[NBINS + tid], (double)ta);
    }
}

// ---------- K4: finalize ----------
__global__ __launch_bounds__(64) void k4_final(const double* __restrict__ bins,
                                               float* __restrict__ out) {
    if (threadIdx.x == 0) {
        double ece = 0.0;
        for (int b = 0; b < NBINS; b++) {
            double avc = bins[b] / (double)W;
            double ava = bins[NBINS + b] / (double)W;
            ece += fabs(avc - ava);
            out[1 + b] = (float)ava;
        }
        out[0] = (float)(ece * ((double)W / (double)NROWS));
    }
}

extern "C" void kernel_launch(void* const* d_in, const int* in_sizes, int n_in,
                              void* d_out, int out_size, void* d_ws, size_t ws_size,
                              hipStream_t stream) {
    const float* x      = (const float*)d_in[0];
    const int*   labels = (const int*)d_in[1];
    float*       out    = (float*)d_out;
    unsigned int* wd    = (unsigned int*)d_ws;

    unsigned int* hist = wd + HIST_DW;
    double*       bins = (double*)(wd + BINS_DW);
    float*        conf = (float*)(wd + CONF_DW);

    // k1 launched twice as a timing probe (idempotent; see k1 comment).
    k1_rowmax<<<2048, 256, 0, stream>>>(x, labels, conf, wd);
    k1_rowmax<<<2048, 256, 0, stream>>>(x, labels, conf, wd);
    k2_hist  <<<128, 512, 0, stream>>>(conf, hist);
    k3_accum <<<512, 256, 0, stream>>>(conf, hist, bins);
    k4_final <<<1, 64, 0, stream>>>(bins, out);
}

// Round 9
// 126.464 us; speedup vs baseline: 2.0603x; 2.0603x over previous
//
#include <hip/hip_runtime.h>
#include <hip/hip_bf16.h>
#include <math.h>
#include <stdint.h>

#define NROWS 1000000
#define NCOLS 100
#define NBINS 20
#define NB    19       // bin boundaries
#define W     50000u   // rows per bin
#define NH    2049     // buckets: 0 = catch-all (<0.5), 1..2048 = [0.5,1) in 2^-12 steps

// ---------- ws layout (dword offsets) ----------
#define HIST_DW 0u       // len 2052
#define BINS_DW 2052u    // len 80 dw = 40 doubles (byte 8208, 8-aligned)
#define ZERO_DW 2132u    // hist+bins zeroed inside k1
#define CONF_DW 2136u    // len 1000000 (byte 8544 = 534*16, 16B-aligned); sign bit = accuracy

__device__ __forceinline__ unsigned int bucket_of(unsigned int bits) {
    // bits = positive-f32 pattern. conf < 0.5 -> 0 (catch-all).
    if (bits < 0x3F000000u) return 0u;
    unsigned int t = (bits >> 12) - 258048u + 1u;   // 1..2048 for [0.5,1)
    return t > 2048u ? 2048u : t;
}

// ---------- K1: LDS-staged row max/argmax ----------------------------------
// Measured (r8 probe): old k1 = 109us (3.7 TB/s). Fix: decouple load from
// reduce. Stage 64 rows (1600 float4) per tile as a DENSE all-lane stream
// (the proven ~6.3 TB/s pattern), then reduce from LDS: thread = (row,
// quarter), stride-101 rows -> 2 lanes/bank (conflict-free, m136), one
// u64 atomicMax per quarter gives exact first-index argmax tie-break.
__global__ __launch_bounds__(256) void k1_rowmax(const float* __restrict__ x,
                                                 const int* __restrict__ labels,
                                                 float* __restrict__ conf,
                                                 unsigned int* __restrict__ zero_region) {
    __shared__ float ldsx[64 * 101];
    __shared__ unsigned long long ldsk[64];
    int tid = threadIdx.x;
    int gtid = blockIdx.x * 256 + tid;
    if (gtid < (int)ZERO_DW) zero_region[gtid] = 0u;   // hist + bins

    const int NTILES = NROWS / 64;  // 15625
    for (int tile = blockIdx.x; tile < NTILES; tile += gridDim.x) {
        // --- stage: 1600 float4 = 64 rows, dense coalesced ---
        const float4* src = reinterpret_cast<const float4*>(x) + (size_t)tile * 1600;
        #pragma unroll
        for (int i = 0; i < 7; i++) {
            int v = i * 256 + tid;
            if (v < 1600) {
                float4 d = src[v];
                int row = v / 25, col = v - row * 25;
                int a = row * 101 + col * 4;
                ldsx[a]     = d.x; ldsx[a + 1] = d.y;
                ldsx[a + 2] = d.z; ldsx[a + 3] = d.w;
            }
        }
        if (tid < 64) ldsk[tid] = 0ull;
        __syncthreads();
        // --- reduce: thread handles quarter q of row r ---
        int r = tid & 63, q = tid >> 6;
        const float* rowp = &ldsx[r * 101 + q * 25];
        float best = rowp[0]; int bi = 0;
        #pragma unroll
        for (int k = 1; k < 25; k++) {
            float vv = rowp[k];
            if (vv > best) { best = vv; bi = k; }
        }
        unsigned long long key =
            ((unsigned long long)__float_as_uint(best) << 32)
            | (unsigned int)(NCOLS - (q * 25 + bi));   // bigger low32 = smaller idx
        atomicMax(&ldsk[r], key);
        __syncthreads();
        if (tid < 64) {
            unsigned long long kk = ldsk[tid];
            unsigned int bits = (unsigned int)(kk >> 32);
            int idx = NCOLS - (int)(kk & 0xFFFFFFFFu);
            int row = tile * 64 + tid;
            if (idx == labels[row]) bits |= 0x80000000u;
            conf[row] = __uint_as_float(bits);
        }
        __syncthreads();   // ldsx reused next tile
    }
}

// ---------- K2: 2049-bucket histogram, per-block LDS ----------
__global__ __launch_bounds__(512) void k2_hist(const float* __restrict__ conf,
                                               unsigned int* __restrict__ hist) {
    __shared__ unsigned int lh[NH];
    for (int i = threadIdx.x; i < NH; i += 512) lh[i] = 0u;
    __syncthreads();
    const uint4* c4 = reinterpret_cast<const uint4*>(conf);
    int stride = gridDim.x * 512;
    for (int i = blockIdx.x * 512 + threadIdx.x; i < NROWS / 4; i += stride) {
        uint4 v = c4[i];
        atomicAdd(&lh[bucket_of(v.x & 0x7FFFFFFFu)], 1u);
        atomicAdd(&lh[bucket_of(v.y & 0x7FFFFFFFu)], 1u);
        atomicAdd(&lh[bucket_of(v.z & 0x7FFFFFFFu)], 1u);
        atomicAdd(&lh[bucket_of(v.w & 0x7FFFFFFFu)], 1u);
    }
    __syncthreads();
    for (int i = threadIdx.x; i < NH; i += 512) {
        unsigned int c = lh[i];
        if (c) atomicAdd(&hist[i], c);
    }
}

// ---------- K3: per-block redundant scan+bounds, then split-accumulate ----
__global__ __launch_bounds__(256) void k3_accum(const float* __restrict__ conf,
                                                const unsigned int* __restrict__ hist,
                                                double* __restrict__ bins) {
    __shared__ unsigned int ptab[NH];   // prefix, later |= (slot+1)<<24 on boundary buckets
    __shared__ unsigned int s[256];
    __shared__ unsigned int bndS[NB];
    __shared__ float sFr[NB];
    __shared__ float sc[4][NBINS], sa[4][NBINS];
    int tid = threadIdx.x;

    // --- scan hist (2049) into ptab ---
    unsigned int loc[9];
    unsigned int tot = 0;
    int base = tid * 9;
    #pragma unroll
    for (int k = 0; k < 9; k++) {
        int idx = base + k;
        unsigned int v = (idx < NH) ? hist[idx] : 0u;
        loc[k] = tot; tot += v;
    }
    s[tid] = tot; __syncthreads();
    for (int off = 1; off < 256; off <<= 1) {
        unsigned int v = (tid >= off) ? s[tid - off] : 0u;
        __syncthreads();
        s[tid] += v;
        __syncthreads();
    }
    unsigned int excl = s[tid] - tot;
    #pragma unroll
    for (int k = 0; k < 9; k++) {
        int idx = base + k;
        if (idx < NH) ptab[idx] = excl + loc[k];
    }
    for (int i = tid; i < 4 * NBINS; i += 256) { (&sc[0][0])[i] = 0.f; (&sa[0][0])[i] = 0.f; }
    __syncthreads();

    // --- phase A: locate boundaries on the CLEAN prefix, save fr ---
    if (tid < NB) {
        unsigned int r = (unsigned int)(tid + 1) * W;
        int lo = 0, hi = NH - 1;
        while (lo < hi) {
            int mid = (lo + hi + 1) >> 1;
            if (ptab[mid] <= r) lo = mid; else hi = mid - 1;
        }
        unsigned int p = ptab[lo];
        if (p < r) {
            unsigned int cnt = ((lo + 1 < NH) ? ptab[lo + 1] : (unsigned int)NROWS) - p;
            bndS[tid] = (unsigned int)lo;
            sFr[tid]  = (float)(r - p) / (float)cnt;
        } else {
            bndS[tid] = 0xFFFFFFFFu;
        }
    }
    __syncthreads();
    // --- phase B: mark boundary buckets ---
    if (tid < NB && bndS[tid] != 0xFFFFFFFFu)
        ptab[bndS[tid]] |= (unsigned int)(tid + 1) << 24;
    __syncthreads();

    // --- main pass ---
    int wid = tid >> 6;
    const uint4* c4 = reinterpret_cast<const uint4*>(conf);
    int stride = gridDim.x * 256;
    for (int i = blockIdx.x * 256 + tid; i < NROWS / 4; i += stride) {
        uint4 q = c4[i];
        unsigned int bs[4] = { q.x, q.y, q.z, q.w };
        #pragma unroll
        for (int j = 0; j < 4; j++) {
            unsigned int raw = bs[j];
            float a = (float)(raw >> 31);
            unsigned int bits = raw & 0x7FFFFFFFu;
            float c = __uint_as_float(bits);
            unsigned int e = ptab[bucket_of(bits)];
            unsigned int t = e >> 24;
            if (t == 0u) {
                unsigned int bin = (e & 0xFFFFFFu) / W;
                atomicAdd(&sc[wid][bin], c); atomicAdd(&sa[wid][bin], a);
            } else {
                float fr = sFr[t - 1];
                atomicAdd(&sc[wid][t - 1], c * fr);
                atomicAdd(&sc[wid][t],     c * (1.f - fr));
                atomicAdd(&sa[wid][t - 1], a * fr);
                atomicAdd(&sa[wid][t],     a * (1.f - fr));
            }
        }
    }
    __syncthreads();
    if (tid < NBINS) {
        float tc = sc[0][tid] + sc[1][tid] + sc[2][tid] + sc[3][tid];
        float ta = sa[0][tid] + sa[1][tid] + sa[2][tid] + sa[3][tid];
        atomicAdd(&bins[tid],         (double)tc);
        atomicAdd(&bins[NBINS + tid], (double)ta);
    }
}

// ---------- K4: finalize ----------
__global__ __launch_bounds__(64) void k4_final(const double* __restrict__ bins,
                                               float* __restrict__ out) {
    if (threadIdx.x == 0) {
        double ece = 0.0;
        for (int b = 0; b < NBINS; b++) {
            double avc = bins[b] / (double)W;
            double ava = bins[NBINS + b] / (double)W;
            ece += fabs(avc - ava);
            out[1 + b] = (float)ava;
        }
        out[0] = (float)(ece * ((double)W / (double)NROWS));
    }
}

extern "C" void kernel_launch(void* const* d_in, const int* in_sizes, int n_in,
                              void* d_out, int out_size, void* d_ws, size_t ws_size,
                              hipStream_t stream) {
    const float* x      = (const float*)d_in[0];
    const int*   labels = (const int*)d_in[1];
    float*       out    = (float*)d_out;
    unsigned int* wd    = (unsigned int*)d_ws;

    unsigned int* hist = wd + HIST_DW;
    double*       bins = (double*)(wd + BINS_DW);
    float*        conf = (float*)(wd + CONF_DW);

    k1_rowmax<<<2048, 256, 0, stream>>>(x, labels, conf, wd);
    k2_hist  <<<128, 512, 0, stream>>>(conf, hist);
    k3_accum <<<512, 256, 0, stream>>>(conf, hist, bins);
    k4_final <<<1, 64, 0, stream>>>(bins, out);
}

// Round 10
// 125.524 us; speedup vs baseline: 2.0758x; 1.0075x over previous
//
#include <hip/hip_runtime.h>
#include <hip/hip_bf16.h>
#include <math.h>
#include <stdint.h>

#define NROWS 1000000
#define NCOLS 100
#define NBINS 20
#define NB    19       // bin boundaries
#define W     50000u   // rows per bin
#define NH    2049     // buckets: 0 = catch-all (<0.5), 1..2048 = [0.5,1) in 2^-12 steps

// ---------- ws layout (dword offsets) ----------
#define HIST_DW 0u       // len 2052
#define BINS_DW 2052u    // len 80 dw = 40 doubles (byte 8208, 8-aligned)
#define ZERO_DW 2132u    // hist+bins zeroed inside k1
#define CONF_DW 2136u    // len 1000000 (byte 8544 = 534*16, 16B-aligned); sign bit = accuracy

__device__ __forceinline__ unsigned int bucket_of(unsigned int bits) {
    // bits = positive-f32 pattern. conf < 0.5 -> 0 (catch-all).
    if (bits < 0x3F000000u) return 0u;
    unsigned int t = (bits >> 12) - 258048u + 1u;   // 1..2048 for [0.5,1)
    return t > 2048u ? 2048u : t;
}

// ---------- K1: LDS-staged row max/argmax, conflict-free layout ------------
// r9 post-mortem: staged k1 = 84us (75% BW); residual = 8-way LDS WRITE
// bank conflict from the stride-101 scalar-write layout. Fix: stage as
// LINEAR float4 (one ds_write_b128/lane, conflict-free), and read with
// thread map r=tid>>2,q=tid&3 so dword addr = 25*tid+k: 25 coprime 32
// -> 64 lanes cover each bank exactly twice (2-way = free, m136).
__global__ __launch_bounds__(256) void k1_rowmax(const float* __restrict__ x,
                                                 const int* __restrict__ labels,
                                                 float* __restrict__ conf,
                                                 unsigned int* __restrict__ zero_region) {
    __shared__ float4 ldsx4[1600];                 // 64 rows x 25 float4, linear
    __shared__ unsigned long long ldsk[64];
    const float* ldsx = (const float*)ldsx4;
    int tid = threadIdx.x;
    int gtid = blockIdx.x * 256 + tid;
    if (gtid < (int)ZERO_DW) zero_region[gtid] = 0u;   // hist + bins

    const int NTILES = NROWS / 64;  // 15625
    for (int tile = blockIdx.x; tile < NTILES; tile += gridDim.x) {
        // --- stage: 1600 float4 = 64 rows, dense coalesced, b128 writes ---
        const float4* src = reinterpret_cast<const float4*>(x) + (size_t)tile * 1600;
        #pragma unroll
        for (int i = 0; i < 7; i++) {
            int v = i * 256 + tid;
            if (v < 1600) ldsx4[v] = src[v];
        }
        if (tid < 64) ldsk[tid] = 0ull;
        __syncthreads();
        // --- reduce: thread = (row r, quarter q); addr = 25*tid + k ---
        int r = tid >> 2, q = tid & 3;
        const float* rowp = ldsx + r * 100 + q * 25;
        float best = rowp[0]; int bi = 0;
        #pragma unroll
        for (int k = 1; k < 25; k++) {
            float vv = rowp[k];
            if (vv > best) { best = vv; bi = k; }
        }
        unsigned long long key =
            ((unsigned long long)__float_as_uint(best) << 32)
            | (unsigned int)(NCOLS - (q * 25 + bi));   // bigger low32 = smaller idx
        atomicMax(&ldsk[r], key);
        __syncthreads();
        if (tid < 64) {
            unsigned long long kk = ldsk[tid];
            unsigned int bits = (unsigned int)(kk >> 32);
            int idx = NCOLS - (int)(kk & 0xFFFFFFFFu);
            int row = tile * 64 + tid;
            if (idx == labels[row]) bits |= 0x80000000u;
            conf[row] = __uint_as_float(bits);
        }
        __syncthreads();   // ldsx reused next tile
    }
}

// ---------- K2: 2049-bucket histogram, per-block LDS ----------
__global__ __launch_bounds__(512) void k2_hist(const float* __restrict__ conf,
                                               unsigned int* __restrict__ hist) {
    __shared__ unsigned int lh[NH];
    for (int i = threadIdx.x; i < NH; i += 512) lh[i] = 0u;
    __syncthreads();
    const uint4* c4 = reinterpret_cast<const uint4*>(conf);
    int stride = gridDim.x * 512;
    for (int i = blockIdx.x * 512 + threadIdx.x; i < NROWS / 4; i += stride) {
        uint4 v = c4[i];
        atomicAdd(&lh[bucket_of(v.x & 0x7FFFFFFFu)], 1u);
        atomicAdd(&lh[bucket_of(v.y & 0x7FFFFFFFu)], 1u);
        atomicAdd(&lh[bucket_of(v.z & 0x7FFFFFFFu)], 1u);
        atomicAdd(&lh[bucket_of(v.w & 0x7FFFFFFFu)], 1u);
    }
    __syncthreads();
    for (int i = threadIdx.x; i < NH; i += 512) {
        unsigned int c = lh[i];
        if (c) atomicAdd(&hist[i], c);
    }
}

// ---------- K3: per-block redundant scan+bounds, then split-accumulate ----
__global__ __launch_bounds__(256) void k3_accum(const float* __restrict__ conf,
                                                const unsigned int* __restrict__ hist,
                                                double* __restrict__ bins) {
    __shared__ unsigned int ptab[NH];   // prefix, later |= (slot+1)<<24 on boundary buckets
    __shared__ unsigned int s[256];
    __shared__ unsigned int bndS[NB];
    __shared__ float sFr[NB];
    __shared__ float sc[4][NBINS], sa[4][NBINS];
    int tid = threadIdx.x;

    // --- scan hist (2049) into ptab ---
    unsigned int loc[9];
    unsigned int tot = 0;
    int base = tid * 9;
    #pragma unroll
    for (int k = 0; k < 9; k++) {
        int idx = base + k;
        unsigned int v = (idx < NH) ? hist[idx] : 0u;
        loc[k] = tot; tot += v;
    }
    s[tid] = tot; __syncthreads();
    for (int off = 1; off < 256; off <<= 1) {
        unsigned int v = (tid >= off) ? s[tid - off] : 0u;
        __syncthreads();
        s[tid] += v;
        __syncthreads();
    }
    unsigned int excl = s[tid] - tot;
    #pragma unroll
    for (int k = 0; k < 9; k++) {
        int idx = base + k;
        if (idx < NH) ptab[idx] = excl + loc[k];
    }
    for (int i = tid; i < 4 * NBINS; i += 256) { (&sc[0][0])[i] = 0.f; (&sa[0][0])[i] = 0.f; }
    __syncthreads();

    // --- phase A: locate boundaries on the CLEAN prefix, save fr ---
    if (tid < NB) {
        unsigned int r = (unsigned int)(tid + 1) * W;
        int lo = 0, hi = NH - 1;
        while (lo < hi) {
            int mid = (lo + hi + 1) >> 1;
            if (ptab[mid] <= r) lo = mid; else hi = mid - 1;
        }
        unsigned int p = ptab[lo];
        if (p < r) {
            unsigned int cnt = ((lo + 1 < NH) ? ptab[lo + 1] : (unsigned int)NROWS) - p;
            bndS[tid] = (unsigned int)lo;
            sFr[tid]  = (float)(r - p) / (float)cnt;
        } else {
            bndS[tid] = 0xFFFFFFFFu;
        }
    }
    __syncthreads();
    // --- phase B: mark boundary buckets ---
    if (tid < NB && bndS[tid] != 0xFFFFFFFFu)
        ptab[bndS[tid]] |= (unsigned int)(tid + 1) << 24;
    __syncthreads();

    // --- main pass ---
    int wid = tid >> 6;
    const uint4* c4 = reinterpret_cast<const uint4*>(conf);
    int stride = gridDim.x * 256;
    for (int i = blockIdx.x * 256 + tid; i < NROWS / 4; i += stride) {
        uint4 q = c4[i];
        unsigned int bs[4] = { q.x, q.y, q.z, q.w };
        #pragma unroll
        for (int j = 0; j < 4; j++) {
            unsigned int raw = bs[j];
            float a = (float)(raw >> 31);
            unsigned int bits = raw & 0x7FFFFFFFu;
            float c = __uint_as_float(bits);
            unsigned int e = ptab[bucket_of(bits)];
            unsigned int t = e >> 24;
            if (t == 0u) {
                unsigned int bin = (e & 0xFFFFFFu) / W;
                atomicAdd(&sc[wid][bin], c); atomicAdd(&sa[wid][bin], a);
            } else {
                float fr = sFr[t - 1];
                atomicAdd(&sc[wid][t - 1], c * fr);
                atomicAdd(&sc[wid][t],     c * (1.f - fr));
                atomicAdd(&sa[wid][t - 1], a * fr);
                atomicAdd(&sa[wid][t],     a * (1.f - fr));
            }
        }
    }
    __syncthreads();
    if (tid < NBINS) {
        float tc = sc[0][tid] + sc[1][tid] + sc[2][tid] + sc[3][tid];
        float ta = sa[0][tid] + sa[1][tid] + sa[2][tid] + sa[3][tid];
        atomicAdd(&bins[tid],         (double)tc);
        atomicAdd(&bins[NBINS + tid], (double)ta);
    }
}

// ---------- K4: finalize ----------
__global__ __launch_bounds__(64) void k4_final(const double* __restrict__ bins,
                                               float* __restrict__ out) {
    if (threadIdx.x == 0) {
        double ece = 0.0;
        for (int b = 0; b < NBINS; b++) {
            double avc = bins[b] / (double)W;
            double ava = bins[NBINS + b] / (double)W;
            ece += fabs(avc - ava);
            out[1 + b] = (float)ava;
        }
        out[0] = (float)(ece * ((double)W / (double)NROWS));
    }
}

extern "C" void kernel_launch(void* const* d_in, const int* in_sizes, int n_in,
                              void* d_out, int out_size, void* d_ws, size_t ws_size,
                              hipStream_t stream) {
    const float* x      = (const float*)d_in[0];
    const int*   labels = (const int*)d_in[1];
    float*       out    = (float*)d_out;
    unsigned int* wd    = (unsigned int*)d_ws;

    unsigned int* hist = wd + HIST_DW;
    double*       bins = (double*)(wd + BINS_DW);
    float*        conf = (float*)(wd + CONF_DW);

    k1_rowmax<<<2048, 256, 0, stream>>>(x, labels, conf, wd);
    k2_hist  <<<128, 512, 0, stream>>>(conf, hist);
    k3_accum <<<512, 256, 0, stream>>>(conf, hist, bins);
    k4_final <<<1, 64, 0, stream>>>(bins, out);
}